// Round 3
// baseline (15439.590 us; speedup 1.0000x reference)
//
#include <hip/hip_runtime.h>

// LAS decoder, dtype-adaptive (fp32 or bf16 inputs, detected on device by
// probing x_mask[0] as u32: fp32 1.0f = 0x3F800000, bf16 {1.0,1.0} = 0x3F803F80).
// If fp32: k_convert canonicalizes all float inputs to bf16 (ws + d_out
// scratch); output store switches to fp32. If bf16: converter no-ops and
// kernels select the original pointers (round-2 path).
//   k_convert : fp32->bf16 canonicalization (18 segments), no-op if bf16
//   k_vwt     : transpose v_w -> vwT (bf16)
//   k_atth    : att_h = eout @ w_w.T + w_b  (bf16 MFMA) -> d_out scratch
//   k_scan    : persistent kernel, 99 steps att-LSTM + attention + dec-LSTM,
//               2 device-scope grid barriers/step, 256 blocks on 256 CUs
//   k_logit   : logit = dout @ cls_w.T + cls_b (bf16 MFMA), store fp32 or bf16

typedef unsigned short u16;
typedef unsigned int u32;
typedef short bf16x8_t __attribute__((ext_vector_type(8)));
typedef float f32x4_t __attribute__((ext_vector_type(4)));

#define NBLK 256
#define LOG2E 1.4426950408889634f
#define FP32_PAT 0x3F800000u

__device__ __forceinline__ float bf2f(u16 h) {
  return __builtin_bit_cast(float, (u32)h << 16);
}
__device__ __forceinline__ u16 f2bf(float f) {
  u32 u = __builtin_bit_cast(u32, f);
  return (u16)((u + 0x7fffu + ((u >> 16) & 1u)) >> 16);
}
__device__ __forceinline__ void bf8_to_f32(uint4 v, float* o) {
  o[0] = __builtin_bit_cast(float, v.x << 16);
  o[1] = __builtin_bit_cast(float, v.x & 0xffff0000u);
  o[2] = __builtin_bit_cast(float, v.y << 16);
  o[3] = __builtin_bit_cast(float, v.y & 0xffff0000u);
  o[4] = __builtin_bit_cast(float, v.z << 16);
  o[5] = __builtin_bit_cast(float, v.z & 0xffff0000u);
  o[6] = __builtin_bit_cast(float, v.w << 16);
  o[7] = __builtin_bit_cast(float, v.w & 0xffff0000u);
}
__device__ __forceinline__ float sigm(float x) {
  float e = __builtin_amdgcn_exp2f(x * -LOG2E);
  return __builtin_amdgcn_rcpf(1.f + e);
}
__device__ __forceinline__ float tanh_(float x) {
  float e = __builtin_amdgcn_exp2f(x * (2.f * LOG2E));
  return 1.f - 2.f * __builtin_amdgcn_rcpf(e + 1.f);
}
__device__ __forceinline__ bool probe_f32(const void* xm) {
  return *(const u32*)xm == FP32_PAT;
}

__device__ __forceinline__ void gbar(u32* bar) {
  __syncthreads();
  __threadfence();
  if (threadIdx.x == 0) {
    u32 gen = __hip_atomic_load(bar + 1, __ATOMIC_RELAXED, __HIP_MEMORY_SCOPE_AGENT);
    u32 old = __hip_atomic_fetch_add(bar, 1u, __ATOMIC_ACQ_REL, __HIP_MEMORY_SCOPE_AGENT);
    if (old == NBLK - 1) {
      __hip_atomic_store(bar, 0u, __ATOMIC_RELAXED, __HIP_MEMORY_SCOPE_AGENT);
      __hip_atomic_fetch_add(bar + 1, 1u, __ATOMIC_RELEASE, __HIP_MEMORY_SCOPE_AGENT);
    } else {
      while (__hip_atomic_load(bar + 1, __ATOMIC_ACQUIRE, __HIP_MEMORY_SCOPE_AGENT) == gen)
        __builtin_amdgcn_s_sleep(2);
    }
  }
  __syncthreads();
}

// ---------------- k_convert ----------------
#define NSEG 18
struct Segs {
  const void* src[NSEG];
  u16* dst[NSEG];
  int n[NSEG];
};
__global__ void k_convert(Segs S, const u32* __restrict__ probe) {
  if (*probe != FP32_PAT) return;
  int seg = blockIdx.y;
  const float* src = (const float*)S.src[seg];
  u16* dst = S.dst[seg];
  int n = S.n[seg];
  for (int i = blockIdx.x * 256 + threadIdx.x; i < n; i += gridDim.x * 256)
    dst[i] = f2bf(src[i]);
}

// ---------------- k_vwt ----------------
__global__ void k_vwt(const void* __restrict__ v_w, u16* __restrict__ vwT,
                      const u32* __restrict__ probe) {
  bool f32 = (*probe == FP32_PAT);
  int idx = blockIdx.x * 256 + threadIdx.x;  // 65536
  int k = idx >> 8, d = idx & 255;
  vwT[idx] = f32 ? f2bf(((const float*)v_w)[d * 256 + k])
                 : ((const u16*)v_w)[d * 256 + k];
}

// ---------------- k_atth ----------------
__global__ __launch_bounds__(256) void k_atth(
    const void* __restrict__ eout_o, const u16* __restrict__ eoutB,
    const void* __restrict__ w_w_o, const u16* __restrict__ w_wB,
    const void* __restrict__ w_b_o, const u16* __restrict__ w_bB,
    u16* __restrict__ atth, const u32* __restrict__ probe) {
  bool f32 = (*probe == FP32_PAT);
  const u16* eout = f32 ? eoutB : (const u16*)eout_o;
  const u16* w_w = f32 ? w_wB : (const u16*)w_w_o;
  const u16* w_b = f32 ? w_bB : (const u16*)w_b_o;
  int wave = threadIdx.x >> 6, lane = threadIdx.x & 63;
  int lm = lane & 15, lk8 = (lane >> 4) * 8;
  int m0 = blockIdx.x * 64 + wave * 16;
  int n0 = blockIdx.y * 64;
  f32x4_t acc[4] = {{0,0,0,0},{0,0,0,0},{0,0,0,0},{0,0,0,0}};
  const u16* arow = eout + (size_t)(m0 + lm) * 256 + lk8;
  for (int k0 = 0; k0 < 256; k0 += 32) {
    bf16x8_t af = *(const bf16x8_t*)(arow + k0);
#pragma unroll
    for (int nt = 0; nt < 4; ++nt) {
      const u16* brow = w_w + (size_t)(n0 + nt * 16 + lm) * 256 + k0 + lk8;
      bf16x8_t bf = *(const bf16x8_t*)brow;
      acc[nt] = __builtin_amdgcn_mfma_f32_16x16x32_bf16(af, bf, acc[nt], 0, 0, 0);
    }
  }
  int rb = (lane >> 4) * 4;
#pragma unroll
  for (int nt = 0; nt < 4; ++nt) {
    int n = n0 + nt * 16 + lm;
    float bias = bf2f(w_b[n]);
#pragma unroll
    for (int r2 = 0; r2 < 4; ++r2) {
      int m = m0 + rb + r2;
      atth[(size_t)m * 256 + n] = f2bf(acc[nt][r2] + bias);
    }
  }
}

// ---------------- k_logit ----------------
__global__ __launch_bounds__(256) void k_logit(
    const u16* __restrict__ dout,
    const void* __restrict__ cls_w_o, const u16* __restrict__ cls_wB,
    const void* __restrict__ cls_b_o, const u16* __restrict__ cls_bB,
    void* __restrict__ outp, const u32* __restrict__ probe) {
  bool f32 = (*probe == FP32_PAT);
  const u16* cls_w = f32 ? cls_wB : (const u16*)cls_w_o;
  const u16* cls_b = f32 ? cls_bB : (const u16*)cls_b_o;
  int wave = threadIdx.x >> 6, lane = threadIdx.x & 63;
  int lm = lane & 15, lk8 = (lane >> 4) * 8;
  int m0 = blockIdx.x * 64 + wave * 16;
  int n0 = blockIdx.y * 64;
  f32x4_t acc[4] = {{0,0,0,0},{0,0,0,0},{0,0,0,0},{0,0,0,0}};
  const u16* arow = dout + (size_t)(m0 + lm) * 768 + lk8;
#pragma unroll 4
  for (int k0 = 0; k0 < 768; k0 += 32) {
    bf16x8_t af = *(const bf16x8_t*)(arow + k0);
#pragma unroll
    for (int nt = 0; nt < 4; ++nt) {
      int n = n0 + nt * 16 + lm;
      int bn = (n < 4233) ? n : 0;
      bf16x8_t bf = *(const bf16x8_t*)(cls_w + (size_t)bn * 768 + k0 + lk8);
      acc[nt] = __builtin_amdgcn_mfma_f32_16x16x32_bf16(af, bf, acc[nt], 0, 0, 0);
    }
  }
  int rb = (lane >> 4) * 4;
#pragma unroll
  for (int nt = 0; nt < 4; ++nt) {
    int n = n0 + nt * 16 + lm;
    if (n < 4233) {
      float bias = bf2f(cls_b[n]);
#pragma unroll
      for (int r2 = 0; r2 < 4; ++r2) {
        int m = m0 + rb + r2;
        float v = acc[nt][r2] + bias;
        if (f32) ((float*)outp)[(size_t)m * 4233 + n] = v;
        else     ((u16*)outp)[(size_t)m * 4233 + n] = f2bf(v);
      }
    }
  }
}

// ---------------- k_scan helpers ----------------
__device__ __forceinline__ void p1_gemm(
    const u16* __restrict__ Wih, const u16* __restrict__ Whh,
    const float (*x_l)[512], const float (*h_l)[256],
    float (*scr)[33], int tid, int hug) {
  int r = tid & 63, kq = tid >> 6;
  int hu = hug * 16 + (r >> 2), gate = r & 3;
  int wrow = gate * 256 + hu;
  float acc[8] = {0, 0, 0, 0, 0, 0, 0, 0};
  const u16* wp = Wih + (size_t)wrow * 512 + kq * 128;
  for (int c = 0; c < 16; ++c) {
    float wf[8];
    bf8_to_f32(*(const uint4*)(wp + c * 8), wf);
#pragma unroll
    for (int b = 0; b < 8; ++b) {
      const float* xp = &x_l[b][kq * 128 + c * 8];
#pragma unroll
      for (int j = 0; j < 8; ++j) acc[b] += wf[j] * xp[j];
    }
  }
  const u16* wp2 = Whh + (size_t)wrow * 256 + kq * 64;
  for (int c = 0; c < 8; ++c) {
    float wf[8];
    bf8_to_f32(*(const uint4*)(wp2 + c * 8), wf);
#pragma unroll
    for (int b = 0; b < 8; ++b) {
      const float* xp = &h_l[b][kq * 64 + c * 8];
#pragma unroll
      for (int j = 0; j < 8; ++j) acc[b] += wf[j] * xp[j];
    }
  }
#pragma unroll
  for (int b = 0; b < 8; ++b) scr[r][b * 4 + kq] = acc[b];
  __syncthreads();
}

// ---------------- k_scan ----------------
__global__ __launch_bounds__(256) void k_scan(
    const void* __restrict__ eout_o, const u16* __restrict__ eoutB,
    const void* __restrict__ x_mask_o, const u16* __restrict__ x_maskB,
    const int* __restrict__ y,
    const void* __restrict__ y_mask_o, const u16* __restrict__ y_maskB,
    const void* __restrict__ emb_o, const u16* __restrict__ embB,
    const void* __restrict__ v_b_o, const u16* __restrict__ v_bB,
    const void* __restrict__ wav_o, const u16* __restrict__ wavB,
    const void* __restrict__ WihA_o, const u16* __restrict__ WihAB,
    const void* __restrict__ WhhA_o, const u16* __restrict__ WhhAB,
    const void* __restrict__ bihA_o, const u16* __restrict__ bihAB,
    const void* __restrict__ bhhA_o, const u16* __restrict__ bhhAB,
    const void* __restrict__ WihD_o, const u16* __restrict__ WihDB,
    const void* __restrict__ WhhD_o, const u16* __restrict__ WhhDB,
    const void* __restrict__ bihD_o, const u16* __restrict__ bihDB,
    const void* __restrict__ bhhD_o, const u16* __restrict__ bhhDB,
    u32* bar, float* h_dec, float* h_att_g, float* g_att,
    float* ctx_part, const u16* __restrict__ vwT, const u16* __restrict__ atth,
    u16* __restrict__ dout) {
  __shared__ float x_l[8][512];
  __shared__ float h_l[8][256];
  __shared__ float scr[64][33];
  __shared__ float hs_l[256], st_l[256], p_l[256], wv_l[256];
  __shared__ float red_l[4];

  const bool f32 = probe_f32(x_mask_o);
  const u16* eout   = f32 ? eoutB  : (const u16*)eout_o;
  const u16* x_mask = f32 ? x_maskB: (const u16*)x_mask_o;
  const u16* y_mask = f32 ? y_maskB: (const u16*)y_mask_o;
  const u16* emb    = f32 ? embB   : (const u16*)emb_o;
  const u16* v_b    = f32 ? v_bB   : (const u16*)v_b_o;
  const u16* wav    = f32 ? wavB   : (const u16*)wav_o;
  const u16* WihA   = f32 ? WihAB  : (const u16*)WihA_o;
  const u16* WhhA   = f32 ? WhhAB  : (const u16*)WhhA_o;
  const u16* bihA   = f32 ? bihAB  : (const u16*)bihA_o;
  const u16* bhhA   = f32 ? bhhAB  : (const u16*)bhhA_o;
  const u16* WihD   = f32 ? WihDB  : (const u16*)WihD_o;
  const u16* WhhD   = f32 ? WhhDB  : (const u16*)WhhD_o;
  const u16* bihD   = f32 ? bihDB  : (const u16*)bihD_o;
  const u16* bhhD   = f32 ? bhhDB  : (const u16*)bhhD_o;

  const int tid = threadIdx.x, blk = blockIdx.x;
  const int bg = blk >> 5, sub = blk & 31;
  const bool is_att = (sub < 16);
  const int hug = is_att ? sub : (sub - 16);
  const int b2 = blk >> 2, tc = blk & 3;

  wv_l[tid] = bf2f(wav[tid]);
  float c_att_reg = 0.f;
  float c_dec_reg = 0.f;

  for (int t = 0; t <= 99; ++t) {
    if (is_att) {
      for (int i = tid; i < 2048; i += 256) {
        int b = i >> 8, d = i & 255;
        int bglob = bg * 8 + b;
        int yv = y[bglob * 100 + t];
        x_l[b][d] = bf2f(emb[(size_t)yv * 256 + d]);
        float cx = 0.f;
        if (t > 0) {
          const float* cp = ctx_part + (size_t)bglob * 4 * 257;
          float s0 = cp[d] + cp[257 + d] + cp[2 * 257 + d] + cp[3 * 257 + d];
          float es = cp[256] + cp[257 + 256] + cp[2 * 257 + 256] + cp[3 * 257 + 256];
          cx = s0 / fmaxf(es, 1e-30f);
        }
        x_l[b][256 + d] = cx;
        h_l[b][d] = h_att_g[bglob * 256 + d];
      }
      __syncthreads();
      if (t >= 1 && tid < 128) {
        int b = tid >> 4, dl = tid & 15;
        int bglob = bg * 8 + b, u = t - 1;
        float ym = bf2f(y_mask[bglob * 100 + u + 1]);
        float ym2 = ym * ym;
        int hu = hug * 16 + dl;
        size_t orow = ((size_t)bglob * 99 + u) * 768;
        dout[orow + hu] = f2bf(h_l[b][hu] * ym2);
        dout[orow + 256 + hu] = f2bf(x_l[b][256 + hu] * ym2);
      }
      if (t < 99) {
        p1_gemm(WihA, WhhA, x_l, h_l, scr, tid, hug);
        if (tid < 128) {
          int b = tid >> 4, dl = tid & 15;
          int bglob = bg * 8 + b;
          float4 q;
          float g4[4];
#pragma unroll
          for (int gate = 0; gate < 4; ++gate) {
            int r2 = dl * 4 + gate;
            int wrow2 = gate * 256 + hug * 16 + dl;
            g4[gate] = scr[r2][b * 4] + scr[r2][b * 4 + 1] + scr[r2][b * 4 + 2] +
                       scr[r2][b * 4 + 3] + bf2f(bihA[wrow2]) + bf2f(bhhA[wrow2]);
          }
          q.x = g4[0]; q.y = g4[1]; q.z = g4[2]; q.w = g4[3];
          *(float4*)&g_att[(size_t)(bglob * 256 + hug * 16 + dl) * 4] = q;
        }
      }
    } else {
      if (t >= 1) {
        int s = t - 1;
        for (int i = tid; i < 2048; i += 256) {
          int b = i >> 8, d = i & 255;
          int bglob = bg * 8 + b;
          float ym = bf2f(y_mask[bglob * 100 + s + 1]);
          const float* cp = ctx_part + (size_t)bglob * 4 * 257;
          float s0 = cp[d] + cp[257 + d] + cp[2 * 257 + d] + cp[3 * 257 + d];
          float es = cp[256] + cp[257 + 256] + cp[2 * 257 + 256] + cp[3 * 257 + 256];
          float cx = s0 / fmaxf(es, 1e-30f);
          x_l[b][d] = h_att_g[bglob * 256 + d] * ym;
          x_l[b][256 + d] = cx * ym;
          h_l[b][d] = h_dec[(s & 1) * 16384 + bglob * 256 + d];
        }
        __syncthreads();
        p1_gemm(WihD, WhhD, x_l, h_l, scr, tid, hug);
        if (tid < 128) {
          int b = tid >> 4, dl = tid & 15;
          int bglob = bg * 8 + b;
          float g4[4];
#pragma unroll
          for (int gate = 0; gate < 4; ++gate) {
            int r2 = dl * 4 + gate;
            int wrow2 = gate * 256 + hug * 16 + dl;
            g4[gate] = scr[r2][b * 4] + scr[r2][b * 4 + 1] + scr[r2][b * 4 + 2] +
                       scr[r2][b * 4 + 3] + bf2f(bihD[wrow2]) + bf2f(bhhD[wrow2]);
          }
          float ii = sigm(g4[0]), ff = sigm(g4[1]), gg = tanh_(g4[2]), oo = sigm(g4[3]);
          float cn = ff * c_dec_reg + ii * gg;
          c_dec_reg = cn;
          float hn = oo * tanh_(cn);
          int hu_g = hug * 16 + dl;
          h_dec[((s + 1) & 1) * 16384 + bglob * 256 + hu_g] = hn;
          float ym = bf2f(y_mask[bglob * 100 + s + 1]);
          dout[((size_t)bglob * 99 + s) * 768 + 512 + hu_g] = f2bf(hn * ym);
        }
      }
    }
    if (t == 99) break;
    gbar(bar);

    {
      int b = b2;
      float4 q = *(const float4*)&g_att[(size_t)(b * 256 + tid) * 4];
      float ii = sigm(q.x), ff = sigm(q.y), gg = tanh_(q.z), oo = sigm(q.w);
      float cn = ff * c_att_reg + ii * gg;
      c_att_reg = cn;
      float hn = oo * tanh_(cn);
      if (tc == 0) h_att_g[b * 256 + tid] = hn;
      hs_l[tid] = hn;
      __syncthreads();
      float st = bf2f(v_b[tid]);
#pragma unroll 8
      for (int k = 0; k < 256; ++k)
        st += hs_l[k] * bf2f(vwT[(size_t)k * 256 + tid]);
      st_l[tid] = st;
      __syncthreads();
      int tg = tc * 256 + tid;
      const u16* ar = atth + ((size_t)(b * 1024 + tg)) * 256;
      float s = 0.f;
#pragma unroll 4
      for (int d8 = 0; d8 < 256; d8 += 8) {
        float af[8];
        bf8_to_f32(*(const uint4*)(ar + d8), af);
#pragma unroll
        for (int j = 0; j < 8; ++j)
          s += wv_l[d8 + j] * tanh_(st_l[d8 + j] + af[j]);
      }
      s += (bf2f(x_mask[b * 1024 + tg]) - 1.f) * 1e30f;
      s = fminf(s, 80.f);
      float p = __builtin_amdgcn_exp2f(s * LOG2E);
      p_l[tid] = p;
      float wsum = p;
#pragma unroll
      for (int off = 32; off; off >>= 1) wsum += __shfl_down(wsum, off);
      if ((tid & 63) == 0) red_l[tid >> 6] = wsum;
      __syncthreads();
      const u16* er = eout + ((size_t)(b * 1024 + tc * 256)) * 256;
      float a0 = 0.f;
#pragma unroll 8
      for (int tt = 0; tt < 256; ++tt)
        a0 += p_l[tt] * bf2f(er[(size_t)tt * 256 + tid]);
      float* cslot = ctx_part + (size_t)(b * 4 + tc) * 257;
      cslot[tid] = a0;
      if (tid == 0) cslot[256] = red_l[0] + red_l[1] + red_l[2] + red_l[3];
    }
    gbar(bar);
  }
}

extern "C" void kernel_launch(void* const* d_in, const int* in_sizes, int n_in,
                              void* d_out, int out_size, void* d_ws, size_t ws_size,
                              hipStream_t stream) {
  (void)in_sizes; (void)n_in; (void)out_size; (void)ws_size;
  const void* eout    = d_in[0];
  const void* x_mask  = d_in[1];
  const int*  y       = (const int*)d_in[2];
  const void* y_mask  = d_in[3];
  const void* emb     = d_in[4];
  const void* w_w     = d_in[5];
  const void* w_b     = d_in[6];
  const void* v_w     = d_in[7];
  const void* v_b     = d_in[8];
  const void* w_att_v = d_in[9];
  const void* Wih_att = d_in[10];
  const void* Whh_att = d_in[11];
  const void* bih_att = d_in[12];
  const void* bhh_att = d_in[13];
  const void* Wih_dec = d_in[14];
  const void* Whh_dec = d_in[15];
  const void* bih_dec = d_in[16];
  const void* bhh_dec = d_in[17];
  const void* cls_w   = d_in[18];
  const void* cls_b   = d_in[19];
  const u32* probe = (const u32*)x_mask;

  // d_out scratch: atth (16,777,216 u16) then eoutB (16,777,216 u16; only
  // written in fp32 mode where d_out is 107 MB). Both dead before k_logit.
  u16* atth  = (u16*)d_out;
  u16* eoutB = atth + 16777216;

  // ws layout (bytes), total ~22.7 MB
  char* w = (char*)d_ws;
  u32*   bar      = (u32*)(w + 0);
  float* h_dec    = (float*)(w + 256);
  float* h_att_g  = (float*)(w + 131328);
  const size_t ZB = 196864;
  float* g_att    = (float*)(w + 196864);
  float* ctx_part = (float*)(w + 459008);
  u16*   vwT      = (u16*)(w + 722176);
  u16*   dout     = (u16*)(w + 853248);      // ends 10,585,344
  u16*   embB     = (u16*)(w + 10585344);    // 1,083,648
  u16*   WihAB    = (u16*)(w + 12752640);    // 524,288
  u16*   WhhAB    = (u16*)(w + 13801216);    // 262,144
  u16*   WihDB    = (u16*)(w + 14325504);    // 524,288
  u16*   WhhDB    = (u16*)(w + 15374080);    // 262,144
  u16*   bihAB    = (u16*)(w + 15898368);    // 1024
  u16*   bhhAB    = (u16*)(w + 15900416);    // 1024
  u16*   bihDB    = (u16*)(w + 15902464);    // 1024
  u16*   bhhDB    = (u16*)(w + 15904512);    // 1024
  u16*   v_bB     = (u16*)(w + 15906560);    // 256
  u16*   wavB     = (u16*)(w + 15907072);    // 256
  u16*   w_wB     = (u16*)(w + 15907584);    // 65,536
  u16*   w_bB     = (u16*)(w + 16038656);    // 256
  u16*   x_maskB  = (u16*)(w + 16039168);    // 65,536
  u16*   y_maskB  = (u16*)(w + 16170240);    // 6,400
  u16*   cls_wB   = (u16*)(w + 16183040);    // 3,250,944
  u16*   cls_bB   = (u16*)(w + 22684928);    // 4,233 -> ends ~22,693,394

  Segs S;
  const void* srcs[NSEG] = {eout, emb, Wih_att, Whh_att, Wih_dec, Whh_dec,
                            bih_att, bhh_att, bih_dec, bhh_dec, v_b, w_att_v,
                            w_w, w_b, x_mask, y_mask, cls_w, cls_b};
  u16* dsts[NSEG] = {eoutB, embB, WihAB, WhhAB, WihDB, WhhDB,
                     bihAB, bhhAB, bihDB, bhhDB, v_bB, wavB,
                     w_wB, w_bB, x_maskB, y_maskB, cls_wB, cls_bB};
  int ns[NSEG] = {16777216, 1083648, 524288, 262144, 524288, 262144,
                  1024, 1024, 1024, 1024, 256, 256,
                  65536, 256, 65536, 6400, 3250944, 4233};
  for (int i = 0; i < NSEG; ++i) { S.src[i] = srcs[i]; S.dst[i] = dsts[i]; S.n[i] = ns[i]; }

  hipMemsetAsync(d_ws, 0, ZB, stream);
  hipLaunchKernelGGL(k_convert, dim3(4096, NSEG), dim3(256), 0, stream, S, probe);
  hipLaunchKernelGGL(k_vwt, dim3(256), dim3(256), 0, stream, v_w, vwT, probe);
  hipLaunchKernelGGL(k_atth, dim3(1024, 4), dim3(256), 0, stream,
                     eout, eoutB, w_w, w_wB, w_b, w_bB, atth, probe);
  hipLaunchKernelGGL(k_scan, dim3(NBLK), dim3(256), 0, stream,
                     eout, eoutB, x_mask, x_maskB, y, y_mask, y_maskB,
                     emb, embB, v_b, v_bB, w_att_v, wavB,
                     Wih_att, WihAB, Whh_att, WhhAB, bih_att, bihAB, bhh_att, bhhAB,
                     Wih_dec, WihDB, Whh_dec, WhhDB, bih_dec, bihDB, bhh_dec, bhhDB,
                     bar, h_dec, h_att_g, g_att, ctx_part, vwT, atth, dout);
  hipLaunchKernelGGL(k_logit, dim3(99, 67), dim3(256), 0, stream,
                     dout, cls_w, cls_wB, cls_b, cls_bB, d_out, probe);
}

// Round 4
// 11907.273 us; speedup vs baseline: 1.2967x; 1.2967x over previous
//
#include <hip/hip_runtime.h>

// LAS decoder, dtype-adaptive (fp32 or bf16 inputs, probed on device via
// x_mask[0] as u32: fp32 1.0f = 0x3F800000, bf16 pair = 0x3F803F80).
// Round 4: replaced single-counter grid barrier (256 serialized same-line
// device-scope RMWs ~70us each, 2/step -> 14 ms) with a distributed-flag
// barrier: per-block epoch slots on separate 128B lines; thread i of every
// block watches slot i. Also: k_atth stores Ta = tanh(att_h) and the scores
// loop uses tanh(a+b) = (Ta+Ts)/(1+Ta*Ts), removing exp2 from the 16.8M/step
// inner loop.

typedef unsigned short u16;
typedef unsigned int u32;
typedef short bf16x8_t __attribute__((ext_vector_type(8)));
typedef float f32x4_t __attribute__((ext_vector_type(4)));

#define NBLK 256
#define LOG2E 1.4426950408889634f
#define FP32_PAT 0x3F800000u

__device__ __forceinline__ float bf2f(u16 h) {
  return __builtin_bit_cast(float, (u32)h << 16);
}
__device__ __forceinline__ u16 f2bf(float f) {
  u32 u = __builtin_bit_cast(u32, f);
  return (u16)((u + 0x7fffu + ((u >> 16) & 1u)) >> 16);
}
__device__ __forceinline__ void bf8_to_f32(uint4 v, float* o) {
  o[0] = __builtin_bit_cast(float, v.x << 16);
  o[1] = __builtin_bit_cast(float, v.x & 0xffff0000u);
  o[2] = __builtin_bit_cast(float, v.y << 16);
  o[3] = __builtin_bit_cast(float, v.y & 0xffff0000u);
  o[4] = __builtin_bit_cast(float, v.z << 16);
  o[5] = __builtin_bit_cast(float, v.z & 0xffff0000u);
  o[6] = __builtin_bit_cast(float, v.w << 16);
  o[7] = __builtin_bit_cast(float, v.w & 0xffff0000u);
}
__device__ __forceinline__ float sigm(float x) {
  float e = __builtin_amdgcn_exp2f(x * -LOG2E);
  return __builtin_amdgcn_rcpf(1.f + e);
}
__device__ __forceinline__ float tanh_(float x) {
  float e = __builtin_amdgcn_exp2f(x * (2.f * LOG2E));
  return 1.f - 2.f * __builtin_amdgcn_rcpf(e + 1.f);
}
__device__ __forceinline__ bool probe_f32(const void* xm) {
  return *(const u32*)xm == FP32_PAT;
}

// Distributed-flag grid barrier. slots[blk*32] holds block blk's epoch
// (128B stride -> no line sharing; plain stores pipeline in parallel).
// Thread i of every block spins on slot i (one line per watched slot).
__device__ __forceinline__ void gbar2(u32* slots, u32 ep) {
  __syncthreads();
  __threadfence();  // release: publish this block's global stores
  if (threadIdx.x == 0)
    __hip_atomic_store(slots + (size_t)blockIdx.x * 32, ep,
                       __ATOMIC_RELAXED, __HIP_MEMORY_SCOPE_AGENT);
  const u32* s = slots + (size_t)threadIdx.x * 32;
  while (__hip_atomic_load(s, __ATOMIC_RELAXED, __HIP_MEMORY_SCOPE_AGENT) < ep)
    __builtin_amdgcn_s_sleep(1);
  __syncthreads();
  __threadfence();  // acquire: invalidate stale L1/L2 before consuming
}

// ---------------- k_convert ----------------
#define NSEG 18
struct Segs {
  const void* src[NSEG];
  u16* dst[NSEG];
  int n[NSEG];
};
__global__ void k_convert(Segs S, const u32* __restrict__ probe) {
  if (*probe != FP32_PAT) return;
  int seg = blockIdx.y;
  const float* src = (const float*)S.src[seg];
  u16* dst = S.dst[seg];
  int n = S.n[seg];
  for (int i = blockIdx.x * 256 + threadIdx.x; i < n; i += gridDim.x * 256)
    dst[i] = f2bf(src[i]);
}

// ---------------- k_vwt ----------------
__global__ void k_vwt(const void* __restrict__ v_w, u16* __restrict__ vwT,
                      const u32* __restrict__ probe) {
  bool f32 = (*probe == FP32_PAT);
  int idx = blockIdx.x * 256 + threadIdx.x;  // 65536
  int k = idx >> 8, d = idx & 255;
  vwT[idx] = f32 ? f2bf(((const float*)v_w)[d * 256 + k])
                 : ((const u16*)v_w)[d * 256 + k];
}

// ---------------- k_atth: Ta = tanh(eout @ w_w.T + w_b) ----------------
__global__ __launch_bounds__(256) void k_atth(
    const void* __restrict__ eout_o, const u16* __restrict__ eoutB,
    const void* __restrict__ w_w_o, const u16* __restrict__ w_wB,
    const void* __restrict__ w_b_o, const u16* __restrict__ w_bB,
    u16* __restrict__ Ta, const u32* __restrict__ probe) {
  bool f32 = (*probe == FP32_PAT);
  const u16* eout = f32 ? eoutB : (const u16*)eout_o;
  const u16* w_w = f32 ? w_wB : (const u16*)w_w_o;
  const u16* w_b = f32 ? w_bB : (const u16*)w_b_o;
  int wave = threadIdx.x >> 6, lane = threadIdx.x & 63;
  int lm = lane & 15, lk8 = (lane >> 4) * 8;
  int m0 = blockIdx.x * 64 + wave * 16;
  int n0 = blockIdx.y * 64;
  f32x4_t acc[4] = {{0,0,0,0},{0,0,0,0},{0,0,0,0},{0,0,0,0}};
  const u16* arow = eout + (size_t)(m0 + lm) * 256 + lk8;
  for (int k0 = 0; k0 < 256; k0 += 32) {
    bf16x8_t af = *(const bf16x8_t*)(arow + k0);
#pragma unroll
    for (int nt = 0; nt < 4; ++nt) {
      const u16* brow = w_w + (size_t)(n0 + nt * 16 + lm) * 256 + k0 + lk8;
      bf16x8_t bf = *(const bf16x8_t*)brow;
      acc[nt] = __builtin_amdgcn_mfma_f32_16x16x32_bf16(af, bf, acc[nt], 0, 0, 0);
    }
  }
  int rb = (lane >> 4) * 4;
#pragma unroll
  for (int nt = 0; nt < 4; ++nt) {
    int n = n0 + nt * 16 + lm;
    float bias = bf2f(w_b[n]);
#pragma unroll
    for (int r2 = 0; r2 < 4; ++r2) {
      int m = m0 + rb + r2;
      Ta[(size_t)m * 256 + n] = f2bf(tanh_(acc[nt][r2] + bias));
    }
  }
}

// ---------------- k_logit ----------------
__global__ __launch_bounds__(256) void k_logit(
    const u16* __restrict__ dout,
    const void* __restrict__ cls_w_o, const u16* __restrict__ cls_wB,
    const void* __restrict__ cls_b_o, const u16* __restrict__ cls_bB,
    void* __restrict__ outp, const u32* __restrict__ probe) {
  bool f32 = (*probe == FP32_PAT);
  const u16* cls_w = f32 ? cls_wB : (const u16*)cls_w_o;
  const u16* cls_b = f32 ? cls_bB : (const u16*)cls_b_o;
  int wave = threadIdx.x >> 6, lane = threadIdx.x & 63;
  int lm = lane & 15, lk8 = (lane >> 4) * 8;
  int m0 = blockIdx.x * 64 + wave * 16;
  int n0 = blockIdx.y * 64;
  f32x4_t acc[4] = {{0,0,0,0},{0,0,0,0},{0,0,0,0},{0,0,0,0}};
  const u16* arow = dout + (size_t)(m0 + lm) * 768 + lk8;
#pragma unroll 4
  for (int k0 = 0; k0 < 768; k0 += 32) {
    bf16x8_t af = *(const bf16x8_t*)(arow + k0);
#pragma unroll
    for (int nt = 0; nt < 4; ++nt) {
      int n = n0 + nt * 16 + lm;
      int bn = (n < 4233) ? n : 0;
      bf16x8_t bf = *(const bf16x8_t*)(cls_w + (size_t)bn * 768 + k0 + lk8);
      acc[nt] = __builtin_amdgcn_mfma_f32_16x16x32_bf16(af, bf, acc[nt], 0, 0, 0);
    }
  }
  int rb = (lane >> 4) * 4;
#pragma unroll
  for (int nt = 0; nt < 4; ++nt) {
    int n = n0 + nt * 16 + lm;
    if (n < 4233) {
      float bias = bf2f(cls_b[n]);
#pragma unroll
      for (int r2 = 0; r2 < 4; ++r2) {
        int m = m0 + rb + r2;
        float v = acc[nt][r2] + bias;
        if (f32) ((float*)outp)[(size_t)m * 4233 + n] = v;
        else     ((u16*)outp)[(size_t)m * 4233 + n] = f2bf(v);
      }
    }
  }
}

// ---------------- k_scan helpers ----------------
__device__ __forceinline__ void p1_gemm(
    const u16* __restrict__ Wih, const u16* __restrict__ Whh,
    const float (*x_l)[512], const float (*h_l)[256],
    float (*scr)[33], int tid, int hug) {
  int r = tid & 63, kq = tid >> 6;
  int hu = hug * 16 + (r >> 2), gate = r & 3;
  int wrow = gate * 256 + hu;
  float acc[8] = {0, 0, 0, 0, 0, 0, 0, 0};
  const u16* wp = Wih + (size_t)wrow * 512 + kq * 128;
  for (int c = 0; c < 16; ++c) {
    float wf[8];
    bf8_to_f32(*(const uint4*)(wp + c * 8), wf);
#pragma unroll
    for (int b = 0; b < 8; ++b) {
      const float* xp = &x_l[b][kq * 128 + c * 8];
#pragma unroll
      for (int j = 0; j < 8; ++j) acc[b] += wf[j] * xp[j];
    }
  }
  const u16* wp2 = Whh + (size_t)wrow * 256 + kq * 64;
  for (int c = 0; c < 8; ++c) {
    float wf[8];
    bf8_to_f32(*(const uint4*)(wp2 + c * 8), wf);
#pragma unroll
    for (int b = 0; b < 8; ++b) {
      const float* xp = &h_l[b][kq * 64 + c * 8];
#pragma unroll
      for (int j = 0; j < 8; ++j) acc[b] += wf[j] * xp[j];
    }
  }
#pragma unroll
  for (int b = 0; b < 8; ++b) scr[r][b * 4 + kq] = acc[b];
  __syncthreads();
}

// ---------------- k_scan ----------------
__global__ __launch_bounds__(256) void k_scan(
    const void* __restrict__ eout_o, const u16* __restrict__ eoutB,
    const void* __restrict__ x_mask_o, const u16* __restrict__ x_maskB,
    const int* __restrict__ y,
    const void* __restrict__ y_mask_o, const u16* __restrict__ y_maskB,
    const void* __restrict__ emb_o, const u16* __restrict__ embB,
    const void* __restrict__ v_b_o, const u16* __restrict__ v_bB,
    const void* __restrict__ wav_o, const u16* __restrict__ wavB,
    const void* __restrict__ WihA_o, const u16* __restrict__ WihAB,
    const void* __restrict__ WhhA_o, const u16* __restrict__ WhhAB,
    const void* __restrict__ bihA_o, const u16* __restrict__ bihAB,
    const void* __restrict__ bhhA_o, const u16* __restrict__ bhhAB,
    const void* __restrict__ WihD_o, const u16* __restrict__ WihDB,
    const void* __restrict__ WhhD_o, const u16* __restrict__ WhhDB,
    const void* __restrict__ bihD_o, const u16* __restrict__ bihDB,
    const void* __restrict__ bhhD_o, const u16* __restrict__ bhhDB,
    u32* slots, float* h_dec, float* h_att_g, float* g_att,
    float* ctx_part, const u16* __restrict__ vwT, const u16* __restrict__ Ta,
    u16* __restrict__ dout) {
  __shared__ float x_l[8][512];
  __shared__ float h_l[8][256];
  __shared__ float scr[64][33];
  __shared__ float hs_l[256], ts_l[256], p_l[256], wv_l[256];
  __shared__ float red_l[4];

  const bool f32 = probe_f32(x_mask_o);
  const u16* eout   = f32 ? eoutB  : (const u16*)eout_o;
  const u16* x_mask = f32 ? x_maskB: (const u16*)x_mask_o;
  const u16* y_mask = f32 ? y_maskB: (const u16*)y_mask_o;
  const u16* emb    = f32 ? embB   : (const u16*)emb_o;
  const u16* v_b    = f32 ? v_bB   : (const u16*)v_b_o;
  const u16* wav    = f32 ? wavB   : (const u16*)wav_o;
  const u16* WihA   = f32 ? WihAB  : (const u16*)WihA_o;
  const u16* WhhA   = f32 ? WhhAB  : (const u16*)WhhA_o;
  const u16* bihA   = f32 ? bihAB  : (const u16*)bihA_o;
  const u16* bhhA   = f32 ? bhhAB  : (const u16*)bhhA_o;
  const u16* WihD   = f32 ? WihDB  : (const u16*)WihD_o;
  const u16* WhhD   = f32 ? WhhDB  : (const u16*)WhhD_o;
  const u16* bihD   = f32 ? bihDB  : (const u16*)bihD_o;
  const u16* bhhD   = f32 ? bhhDB  : (const u16*)bhhD_o;

  const int tid = threadIdx.x, blk = blockIdx.x;
  const int bg = blk >> 5, sub = blk & 31;
  const bool is_att = (sub < 16);
  const int hug = is_att ? sub : (sub - 16);
  const int b2 = blk >> 2, tc = blk & 3;

  wv_l[tid] = bf2f(wav[tid]);
  float c_att_reg = 0.f;
  float c_dec_reg = 0.f;

  for (int t = 0; t <= 99; ++t) {
    if (is_att) {
      for (int i = tid; i < 2048; i += 256) {
        int b = i >> 8, d = i & 255;
        int bglob = bg * 8 + b;
        int yv = y[bglob * 100 + t];
        x_l[b][d] = bf2f(emb[(size_t)yv * 256 + d]);
        float cx = 0.f;
        if (t > 0) {
          const float* cp = ctx_part + (size_t)bglob * 4 * 257;
          float s0 = cp[d] + cp[257 + d] + cp[2 * 257 + d] + cp[3 * 257 + d];
          float es = cp[256] + cp[257 + 256] + cp[2 * 257 + 256] + cp[3 * 257 + 256];
          cx = s0 / fmaxf(es, 1e-30f);
        }
        x_l[b][256 + d] = cx;
        h_l[b][d] = h_att_g[bglob * 256 + d];
      }
      __syncthreads();
      if (t >= 1 && tid < 128) {
        int b = tid >> 4, dl = tid & 15;
        int bglob = bg * 8 + b, u = t - 1;
        float ym = bf2f(y_mask[bglob * 100 + u + 1]);
        float ym2 = ym * ym;
        int hu = hug * 16 + dl;
        size_t orow = ((size_t)bglob * 99 + u) * 768;
        dout[orow + hu] = f2bf(h_l[b][hu] * ym2);
        dout[orow + 256 + hu] = f2bf(x_l[b][256 + hu] * ym2);
      }
      if (t < 99) {
        p1_gemm(WihA, WhhA, x_l, h_l, scr, tid, hug);
        if (tid < 128) {
          int b = tid >> 4, dl = tid & 15;
          int bglob = bg * 8 + b;
          float4 q;
          float g4[4];
#pragma unroll
          for (int gate = 0; gate < 4; ++gate) {
            int r2 = dl * 4 + gate;
            int wrow2 = gate * 256 + hug * 16 + dl;
            g4[gate] = scr[r2][b * 4] + scr[r2][b * 4 + 1] + scr[r2][b * 4 + 2] +
                       scr[r2][b * 4 + 3] + bf2f(bihA[wrow2]) + bf2f(bhhA[wrow2]);
          }
          q.x = g4[0]; q.y = g4[1]; q.z = g4[2]; q.w = g4[3];
          *(float4*)&g_att[(size_t)(bglob * 256 + hug * 16 + dl) * 4] = q;
        }
      }
    } else {
      if (t >= 1) {
        int s = t - 1;
        for (int i = tid; i < 2048; i += 256) {
          int b = i >> 8, d = i & 255;
          int bglob = bg * 8 + b;
          float ym = bf2f(y_mask[bglob * 100 + s + 1]);
          const float* cp = ctx_part + (size_t)bglob * 4 * 257;
          float s0 = cp[d] + cp[257 + d] + cp[2 * 257 + d] + cp[3 * 257 + d];
          float es = cp[256] + cp[257 + 256] + cp[2 * 257 + 256] + cp[3 * 257 + 256];
          float cx = s0 / fmaxf(es, 1e-30f);
          x_l[b][d] = h_att_g[bglob * 256 + d] * ym;
          x_l[b][256 + d] = cx * ym;
          h_l[b][d] = h_dec[(s & 1) * 16384 + bglob * 256 + d];
        }
        __syncthreads();
        p1_gemm(WihD, WhhD, x_l, h_l, scr, tid, hug);
        if (tid < 128) {
          int b = tid >> 4, dl = tid & 15;
          int bglob = bg * 8 + b;
          float g4[4];
#pragma unroll
          for (int gate = 0; gate < 4; ++gate) {
            int r2 = dl * 4 + gate;
            int wrow2 = gate * 256 + hug * 16 + dl;
            g4[gate] = scr[r2][b * 4] + scr[r2][b * 4 + 1] + scr[r2][b * 4 + 2] +
                       scr[r2][b * 4 + 3] + bf2f(bihD[wrow2]) + bf2f(bhhD[wrow2]);
          }
          float ii = sigm(g4[0]), ff = sigm(g4[1]), gg = tanh_(g4[2]), oo = sigm(g4[3]);
          float cn = ff * c_dec_reg + ii * gg;
          c_dec_reg = cn;
          float hn = oo * tanh_(cn);
          int hu_g = hug * 16 + dl;
          h_dec[((s + 1) & 1) * 16384 + bglob * 256 + hu_g] = hn;
          float ym = bf2f(y_mask[bglob * 100 + s + 1]);
          dout[((size_t)bglob * 99 + s) * 768 + 512 + hu_g] = f2bf(hn * ym);
        }
      }
    }
    if (t == 99) break;
    gbar2(slots, (u32)(2 * t + 1));

    {
      int b = b2;
      float4 q = *(const float4*)&g_att[(size_t)(b * 256 + tid) * 4];
      float ii = sigm(q.x), ff = sigm(q.y), gg = tanh_(q.z), oo = sigm(q.w);
      float cn = ff * c_att_reg + ii * gg;
      c_att_reg = cn;
      float hn = oo * tanh_(cn);
      if (tc == 0) h_att_g[b * 256 + tid] = hn;
      hs_l[tid] = hn;
      __syncthreads();
      float st = bf2f(v_b[tid]);
#pragma unroll 8
      for (int k = 0; k < 256; ++k)
        st += hs_l[k] * bf2f(vwT[(size_t)k * 256 + tid]);
      ts_l[tid] = tanh_(st);
      __syncthreads();
      int tg = tc * 256 + tid;
      const u16* ar = Ta + ((size_t)(b * 1024 + tg)) * 256;
      float s = 0.f;
#pragma unroll 4
      for (int d8 = 0; d8 < 256; d8 += 8) {
        float af[8];
        bf8_to_f32(*(const uint4*)(ar + d8), af);
#pragma unroll
        for (int j = 0; j < 8; ++j) {
          // tanh(st+a) = (Ts+Ta)/(1+Ts*Ta)
          float ts = ts_l[d8 + j], ta = af[j];
          float u = ts + ta;
          float v = fmaf(ts, ta, 1.f);
          s = fmaf(wv_l[d8 + j] * u, __builtin_amdgcn_rcpf(fmaxf(v, 1e-6f)), s);
        }
      }
      s += (bf2f(x_mask[b * 1024 + tg]) - 1.f) * 1e30f;
      s = fminf(s, 80.f);
      float p = __builtin_amdgcn_exp2f(s * LOG2E);
      p_l[tid] = p;
      float wsum = p;
#pragma unroll
      for (int off = 32; off; off >>= 1) wsum += __shfl_down(wsum, off);
      if ((tid & 63) == 0) red_l[tid >> 6] = wsum;
      __syncthreads();
      const u16* er = eout + ((size_t)(b * 1024 + tc * 256)) * 256;
      float a0 = 0.f;
#pragma unroll 8
      for (int tt = 0; tt < 256; ++tt)
        a0 += p_l[tt] * bf2f(er[(size_t)tt * 256 + tid]);
      float* cslot = ctx_part + (size_t)(b * 4 + tc) * 257;
      cslot[tid] = a0;
      if (tid == 0) cslot[256] = red_l[0] + red_l[1] + red_l[2] + red_l[3];
    }
    gbar2(slots, (u32)(2 * t + 2));
  }
}

extern "C" void kernel_launch(void* const* d_in, const int* in_sizes, int n_in,
                              void* d_out, int out_size, void* d_ws, size_t ws_size,
                              hipStream_t stream) {
  (void)in_sizes; (void)n_in; (void)out_size; (void)ws_size;
  const void* eout    = d_in[0];
  const void* x_mask  = d_in[1];
  const int*  y       = (const int*)d_in[2];
  const void* y_mask  = d_in[3];
  const void* emb     = d_in[4];
  const void* w_w     = d_in[5];
  const void* w_b     = d_in[6];
  const void* v_w     = d_in[7];
  const void* v_b     = d_in[8];
  const void* w_att_v = d_in[9];
  const void* Wih_att = d_in[10];
  const void* Whh_att = d_in[11];
  const void* bih_att = d_in[12];
  const void* bhh_att = d_in[13];
  const void* Wih_dec = d_in[14];
  const void* Whh_dec = d_in[15];
  const void* bih_dec = d_in[16];
  const void* bhh_dec = d_in[17];
  const void* cls_w   = d_in[18];
  const void* cls_b   = d_in[19];
  const u32* probe = (const u32*)x_mask;

  // d_out scratch: Ta (16,777,216 u16) then eoutB (16,777,216 u16; only
  // written in fp32 mode where d_out is 107 MB). Both dead before k_logit.
  u16* TaB   = (u16*)d_out;
  u16* eoutB = TaB + 16777216;

  // ws layout (bytes), total ~22.7 MB
  char* w = (char*)d_ws;
  u32*   slots    = (u32*)(w + 0);           // 256 slots * 128B = 32768, zeroed
  float* h_dec    = (float*)(w + 32768);     // 131072, zeroed
  float* h_att_g  = (float*)(w + 163840);    // 65536, zeroed
  const size_t ZB = 229376;
  float* g_att    = (float*)(w + 229376);    // 262144
  float* ctx_part = (float*)(w + 491520);    // 263168
  u16*   vwT      = (u16*)(w + 754688);      // 131072
  u16*   dout     = (u16*)(w + 885760);      // 9732096 -> 10617856
  u16*   embB     = (u16*)(w + 10617856);    // 2167296
  u16*   WihAB    = (u16*)(w + 12785152);    // 1048576
  u16*   WhhAB    = (u16*)(w + 13833728);    // 524288
  u16*   WihDB    = (u16*)(w + 14358016);    // 1048576
  u16*   WhhDB    = (u16*)(w + 15406592);    // 524288
  u16*   bihAB    = (u16*)(w + 15930880);    // 2048
  u16*   bhhAB    = (u16*)(w + 15932928);    // 2048
  u16*   bihDB    = (u16*)(w + 15934976);    // 2048
  u16*   bhhDB    = (u16*)(w + 15937024);    // 2048
  u16*   v_bB     = (u16*)(w + 15939072);    // 512
  u16*   wavB     = (u16*)(w + 15939584);    // 512
  u16*   w_wB     = (u16*)(w + 15940096);    // 131072
  u16*   w_bB     = (u16*)(w + 16071168);    // 512
  u16*   x_maskB  = (u16*)(w + 16071680);    // 131072
  u16*   y_maskB  = (u16*)(w + 16202752);    // 12800
  u16*   cls_wB   = (u16*)(w + 16215552);    // 6501888
  u16*   cls_bB   = (u16*)(w + 22717440);    // 8466 -> ends 22725906

  Segs S;
  const void* srcs[NSEG] = {eout, emb, Wih_att, Whh_att, Wih_dec, Whh_dec,
                            bih_att, bhh_att, bih_dec, bhh_dec, v_b, w_att_v,
                            w_w, w_b, x_mask, y_mask, cls_w, cls_b};
  u16* dsts[NSEG] = {eoutB, embB, WihAB, WhhAB, WihDB, WhhDB,
                     bihAB, bhhAB, bihDB, bhhDB, v_bB, wavB,
                     w_wB, w_bB, x_maskB, y_maskB, cls_wB, cls_bB};
  int ns[NSEG] = {16777216, 1083648, 524288, 262144, 524288, 262144,
                  1024, 1024, 1024, 1024, 256, 256,
                  65536, 256, 65536, 6400, 3250944, 4233};
  for (int i = 0; i < NSEG; ++i) { S.src[i] = srcs[i]; S.dst[i] = dsts[i]; S.n[i] = ns[i]; }

  hipMemsetAsync(d_ws, 0, ZB, stream);
  hipLaunchKernelGGL(k_convert, dim3(4096, NSEG), dim3(256), 0, stream, S, probe);
  hipLaunchKernelGGL(k_vwt, dim3(256), dim3(256), 0, stream, v_w, vwT, probe);
  hipLaunchKernelGGL(k_atth, dim3(1024, 4), dim3(256), 0, stream,
                     eout, eoutB, w_w, w_wB, w_b, w_bB, TaB, probe);
  hipLaunchKernelGGL(k_scan, dim3(NBLK), dim3(256), 0, stream,
                     eout, eoutB, x_mask, x_maskB, y, y_mask, y_maskB,
                     emb, embB, v_b, v_bB, w_att_v, wavB,
                     Wih_att, WihAB, Whh_att, WhhAB, bih_att, bihAB, bhh_att, bhhAB,
                     Wih_dec, WihDB, Whh_dec, WhhDB, bih_dec, bihDB, bhh_dec, bhhDB,
                     slots, h_dec, h_att_g, g_att, ctx_part, vwT, TaB, dout);
  hipLaunchKernelGGL(k_logit, dim3(99, 67), dim3(256), 0, stream,
                     dout, cls_w, cls_wB, cls_b, cls_bB, d_out, probe);
}

// Round 5
// 4612.397 us; speedup vs baseline: 3.3474x; 2.5816x over previous
//
#include <hip/hip_runtime.h>

// LAS decoder, dtype-adaptive (fp32 or bf16 inputs, probed on device via
// x_mask[0] as u32: fp32 1.0f = 0x3F800000, bf16 pair = 0x3F803F80).
// Round 5: removed __threadfence() from the grid barrier (agent-scope fences
// emit buffer_wbl2/buffer_inv = full per-XCD L2 writeback/invalidate, which
// made EVERY step refetch 37.5 MB through L2 -> 114us/step, the round-4
// bottleneck per FETCH_SIZE=3.7GB). Cross-block communication now uses
// relaxed agent-scope atomic load/store (sc1 ops that bypass the
// non-coherent L2), so read-only bulk (Ta/eout/vwT/weights) stays L2-hot.
// Ordering: compiler emits s_waitcnt vmcnt(0) before s_barrier, so all comm
// stores are at the coherence point before the barrier flag store issues.

typedef unsigned short u16;
typedef unsigned int u32;
typedef short bf16x8_t __attribute__((ext_vector_type(8)));
typedef float f32x4_t __attribute__((ext_vector_type(4)));

#define NBLK 256
#define LOG2E 1.4426950408889634f
#define FP32_PAT 0x3F800000u

__device__ __forceinline__ float bf2f(u16 h) {
  return __builtin_bit_cast(float, (u32)h << 16);
}
__device__ __forceinline__ u16 f2bf(float f) {
  u32 u = __builtin_bit_cast(u32, f);
  return (u16)((u + 0x7fffu + ((u >> 16) & 1u)) >> 16);
}
__device__ __forceinline__ void bf8_to_f32(uint4 v, float* o) {
  o[0] = __builtin_bit_cast(float, v.x << 16);
  o[1] = __builtin_bit_cast(float, v.x & 0xffff0000u);
  o[2] = __builtin_bit_cast(float, v.y << 16);
  o[3] = __builtin_bit_cast(float, v.y & 0xffff0000u);
  o[4] = __builtin_bit_cast(float, v.z << 16);
  o[5] = __builtin_bit_cast(float, v.z & 0xffff0000u);
  o[6] = __builtin_bit_cast(float, v.w << 16);
  o[7] = __builtin_bit_cast(float, v.w & 0xffff0000u);
}
__device__ __forceinline__ float sigm(float x) {
  float e = __builtin_amdgcn_exp2f(x * -LOG2E);
  return __builtin_amdgcn_rcpf(1.f + e);
}
__device__ __forceinline__ float tanh_(float x) {
  float e = __builtin_amdgcn_exp2f(x * (2.f * LOG2E));
  return 1.f - 2.f * __builtin_amdgcn_rcpf(e + 1.f);
}
__device__ __forceinline__ bool probe_f32(const void* xm) {
  return *(const u32*)xm == FP32_PAT;
}

// Coherent (agent-scope, L2-bypassing) load/store for cross-block data.
__device__ __forceinline__ void gstore(float* p, float v) {
  __hip_atomic_store((u32*)p, __builtin_bit_cast(u32, v),
                     __ATOMIC_RELAXED, __HIP_MEMORY_SCOPE_AGENT);
}
__device__ __forceinline__ float gload(const float* p) {
  u32 u = __hip_atomic_load((const u32*)p, __ATOMIC_RELAXED,
                            __HIP_MEMORY_SCOPE_AGENT);
  return __builtin_bit_cast(float, u);
}

// Distributed-flag grid barrier, NO cache-flushing fences. slots[blk*32]
// holds block blk's epoch (128B stride). Thread i (<256) spins on slot i.
__device__ __forceinline__ void gbar2(u32* slots, u32 ep) {
  __syncthreads();  // compiler emits s_waitcnt vmcnt(0) before s_barrier:
                    // all this block's sc1 comm stores are acked first
  if (threadIdx.x == 0)
    __hip_atomic_store(slots + (size_t)blockIdx.x * 32, ep,
                       __ATOMIC_RELAXED, __HIP_MEMORY_SCOPE_AGENT);
  const u32* s = slots + (size_t)threadIdx.x * 32;
  while (__hip_atomic_load(s, __ATOMIC_RELAXED, __HIP_MEMORY_SCOPE_AGENT) < ep)
    __builtin_amdgcn_s_sleep(2);
  __syncthreads();
}

// ---------------- k_convert ----------------
#define NSEG 18
struct Segs {
  const void* src[NSEG];
  u16* dst[NSEG];
  int n[NSEG];
};
__global__ void k_convert(Segs S, const u32* __restrict__ probe) {
  if (*probe != FP32_PAT) return;
  int seg = blockIdx.y;
  const float* src = (const float*)S.src[seg];
  u16* dst = S.dst[seg];
  int n = S.n[seg];
  for (int i = blockIdx.x * 256 + threadIdx.x; i < n; i += gridDim.x * 256)
    dst[i] = f2bf(src[i]);
}

// ---------------- k_vwt ----------------
__global__ void k_vwt(const void* __restrict__ v_w, u16* __restrict__ vwT,
                      const u32* __restrict__ probe) {
  bool f32 = (*probe == FP32_PAT);
  int idx = blockIdx.x * 256 + threadIdx.x;  // 65536
  int k = idx >> 8, d = idx & 255;
  vwT[idx] = f32 ? f2bf(((const float*)v_w)[d * 256 + k])
                 : ((const u16*)v_w)[d * 256 + k];
}

// ---------------- k_atth: Ta = tanh(eout @ w_w.T + w_b) ----------------
__global__ __launch_bounds__(256) void k_atth(
    const void* __restrict__ eout_o, const u16* __restrict__ eoutB,
    const void* __restrict__ w_w_o, const u16* __restrict__ w_wB,
    const void* __restrict__ w_b_o, const u16* __restrict__ w_bB,
    u16* __restrict__ Ta, const u32* __restrict__ probe) {
  bool f32 = (*probe == FP32_PAT);
  const u16* eout = f32 ? eoutB : (const u16*)eout_o;
  const u16* w_w = f32 ? w_wB : (const u16*)w_w_o;
  const u16* w_b = f32 ? w_bB : (const u16*)w_b_o;
  int wave = threadIdx.x >> 6, lane = threadIdx.x & 63;
  int lm = lane & 15, lk8 = (lane >> 4) * 8;
  int m0 = blockIdx.x * 64 + wave * 16;
  int n0 = blockIdx.y * 64;
  f32x4_t acc[4] = {{0,0,0,0},{0,0,0,0},{0,0,0,0},{0,0,0,0}};
  const u16* arow = eout + (size_t)(m0 + lm) * 256 + lk8;
  for (int k0 = 0; k0 < 256; k0 += 32) {
    bf16x8_t af = *(const bf16x8_t*)(arow + k0);
#pragma unroll
    for (int nt = 0; nt < 4; ++nt) {
      const u16* brow = w_w + (size_t)(n0 + nt * 16 + lm) * 256 + k0 + lk8;
      bf16x8_t bf = *(const bf16x8_t*)brow;
      acc[nt] = __builtin_amdgcn_mfma_f32_16x16x32_bf16(af, bf, acc[nt], 0, 0, 0);
    }
  }
  int rb = (lane >> 4) * 4;
#pragma unroll
  for (int nt = 0; nt < 4; ++nt) {
    int n = n0 + nt * 16 + lm;
    float bias = bf2f(w_b[n]);
#pragma unroll
    for (int r2 = 0; r2 < 4; ++r2) {
      int m = m0 + rb + r2;
      Ta[(size_t)m * 256 + n] = f2bf(tanh_(acc[nt][r2] + bias));
    }
  }
}

// ---------------- k_logit ----------------
__global__ __launch_bounds__(256) void k_logit(
    const u16* __restrict__ dout,
    const void* __restrict__ cls_w_o, const u16* __restrict__ cls_wB,
    const void* __restrict__ cls_b_o, const u16* __restrict__ cls_bB,
    void* __restrict__ outp, const u32* __restrict__ probe) {
  bool f32 = (*probe == FP32_PAT);
  const u16* cls_w = f32 ? cls_wB : (const u16*)cls_w_o;
  const u16* cls_b = f32 ? cls_bB : (const u16*)cls_b_o;
  int wave = threadIdx.x >> 6, lane = threadIdx.x & 63;
  int lm = lane & 15, lk8 = (lane >> 4) * 8;
  int m0 = blockIdx.x * 64 + wave * 16;
  int n0 = blockIdx.y * 64;
  f32x4_t acc[4] = {{0,0,0,0},{0,0,0,0},{0,0,0,0},{0,0,0,0}};
  const u16* arow = dout + (size_t)(m0 + lm) * 768 + lk8;
#pragma unroll 4
  for (int k0 = 0; k0 < 768; k0 += 32) {
    bf16x8_t af = *(const bf16x8_t*)(arow + k0);
#pragma unroll
    for (int nt = 0; nt < 4; ++nt) {
      int n = n0 + nt * 16 + lm;
      int bn = (n < 4233) ? n : 0;
      bf16x8_t bf = *(const bf16x8_t*)(cls_w + (size_t)bn * 768 + k0 + lk8);
      acc[nt] = __builtin_amdgcn_mfma_f32_16x16x32_bf16(af, bf, acc[nt], 0, 0, 0);
    }
  }
  int rb = (lane >> 4) * 4;
#pragma unroll
  for (int nt = 0; nt < 4; ++nt) {
    int n = n0 + nt * 16 + lm;
    if (n < 4233) {
      float bias = bf2f(cls_b[n]);
#pragma unroll
      for (int r2 = 0; r2 < 4; ++r2) {
        int m = m0 + rb + r2;
        float v = acc[nt][r2] + bias;
        if (f32) ((float*)outp)[(size_t)m * 4233 + n] = v;
        else     ((u16*)outp)[(size_t)m * 4233 + n] = f2bf(v);
      }
    }
  }
}

// ---------------- k_scan helpers ----------------
__device__ __forceinline__ void p1_gemm(
    const u16* __restrict__ Wih, const u16* __restrict__ Whh,
    const float (*x_l)[512], const float (*h_l)[256],
    float (*scr)[33], int tid, int hug) {
  int r = tid & 63, kq = tid >> 6;
  int hu = hug * 16 + (r >> 2), gate = r & 3;
  int wrow = gate * 256 + hu;
  float acc[8] = {0, 0, 0, 0, 0, 0, 0, 0};
  const u16* wp = Wih + (size_t)wrow * 512 + kq * 128;
#pragma unroll 4
  for (int c = 0; c < 16; ++c) {
    float wf[8];
    bf8_to_f32(*(const uint4*)(wp + c * 8), wf);
#pragma unroll
    for (int b = 0; b < 8; ++b) {
      const float* xp = &x_l[b][kq * 128 + c * 8];
#pragma unroll
      for (int j = 0; j < 8; ++j) acc[b] += wf[j] * xp[j];
    }
  }
  const u16* wp2 = Whh + (size_t)wrow * 256 + kq * 64;
#pragma unroll 4
  for (int c = 0; c < 8; ++c) {
    float wf[8];
    bf8_to_f32(*(const uint4*)(wp2 + c * 8), wf);
#pragma unroll
    for (int b = 0; b < 8; ++b) {
      const float* xp = &h_l[b][kq * 64 + c * 8];
#pragma unroll
      for (int j = 0; j < 8; ++j) acc[b] += wf[j] * xp[j];
    }
  }
#pragma unroll
  for (int b = 0; b < 8; ++b) scr[r][b * 4 + kq] = acc[b];
  __syncthreads();
}

// ---------------- k_scan ----------------
__global__ __launch_bounds__(256) void k_scan(
    const void* __restrict__ eout_o, const u16* __restrict__ eoutB,
    const void* __restrict__ x_mask_o, const u16* __restrict__ x_maskB,
    const int* __restrict__ y,
    const void* __restrict__ y_mask_o, const u16* __restrict__ y_maskB,
    const void* __restrict__ emb_o, const u16* __restrict__ embB,
    const void* __restrict__ v_b_o, const u16* __restrict__ v_bB,
    const void* __restrict__ wav_o, const u16* __restrict__ wavB,
    const void* __restrict__ WihA_o, const u16* __restrict__ WihAB,
    const void* __restrict__ WhhA_o, const u16* __restrict__ WhhAB,
    const void* __restrict__ bihA_o, const u16* __restrict__ bihAB,
    const void* __restrict__ bhhA_o, const u16* __restrict__ bhhAB,
    const void* __restrict__ WihD_o, const u16* __restrict__ WihDB,
    const void* __restrict__ WhhD_o, const u16* __restrict__ WhhDB,
    const void* __restrict__ bihD_o, const u16* __restrict__ bihDB,
    const void* __restrict__ bhhD_o, const u16* __restrict__ bhhDB,
    u32* slots, float* h_dec, float* h_att_g, float* g_att,
    float* ctx_part, const u16* __restrict__ vwT, const u16* __restrict__ Ta,
    u16* __restrict__ dout) {
  __shared__ float x_l[8][512];
  __shared__ float h_l[8][256];
  __shared__ float scr[64][33];
  __shared__ float hs_l[256], ts_l[256], p_l[256], wv_l[256];
  __shared__ float red_l[4];

  const bool f32 = probe_f32(x_mask_o);
  const u16* eout   = f32 ? eoutB  : (const u16*)eout_o;
  const u16* x_mask = f32 ? x_maskB: (const u16*)x_mask_o;
  const u16* y_mask = f32 ? y_maskB: (const u16*)y_mask_o;
  const u16* emb    = f32 ? embB   : (const u16*)emb_o;
  const u16* v_b    = f32 ? v_bB   : (const u16*)v_b_o;
  const u16* wav    = f32 ? wavB   : (const u16*)wav_o;
  const u16* WihA   = f32 ? WihAB  : (const u16*)WihA_o;
  const u16* WhhA   = f32 ? WhhAB  : (const u16*)WhhA_o;
  const u16* bihA   = f32 ? bihAB  : (const u16*)bihA_o;
  const u16* bhhA   = f32 ? bhhAB  : (const u16*)bhhA_o;
  const u16* WihD   = f32 ? WihDB  : (const u16*)WihD_o;
  const u16* WhhD   = f32 ? WhhDB  : (const u16*)WhhD_o;
  const u16* bihD   = f32 ? bihDB  : (const u16*)bihD_o;
  const u16* bhhD   = f32 ? bhhDB  : (const u16*)bhhD_o;

  const int tid = threadIdx.x, blk = blockIdx.x;
  const int bg = blk >> 5, sub = blk & 31;
  const bool is_att = (sub < 16);
  const int hug = is_att ? sub : (sub - 16);
  const int b2 = blk >> 2, tc = blk & 3;

  wv_l[tid] = bf2f(wav[tid]);
  float c_att_reg = 0.f;
  float c_dec_reg = 0.f;

  for (int t = 0; t <= 99; ++t) {
    if (is_att) {
      for (int i = tid; i < 2048; i += 256) {
        int b = i >> 8, d = i & 255;
        int bglob = bg * 8 + b;
        int yv = y[bglob * 100 + t];
        x_l[b][d] = bf2f(emb[(size_t)yv * 256 + d]);
        float cx = 0.f;
        if (t > 0) {
          const float* cp = ctx_part + (size_t)bglob * 4 * 257;
          float s0 = gload(cp + d) + gload(cp + 257 + d) +
                     gload(cp + 2 * 257 + d) + gload(cp + 3 * 257 + d);
          float es = gload(cp + 256) + gload(cp + 257 + 256) +
                     gload(cp + 2 * 257 + 256) + gload(cp + 3 * 257 + 256);
          cx = s0 / fmaxf(es, 1e-30f);
        }
        x_l[b][256 + d] = cx;
        h_l[b][d] = gload(h_att_g + bglob * 256 + d);
      }
      __syncthreads();
      if (t >= 1 && tid < 128) {
        int b = tid >> 4, dl = tid & 15;
        int bglob = bg * 8 + b, u = t - 1;
        float ym = bf2f(y_mask[bglob * 100 + u + 1]);
        float ym2 = ym * ym;
        int hu = hug * 16 + dl;
        size_t orow = ((size_t)bglob * 99 + u) * 768;
        dout[orow + hu] = f2bf(h_l[b][hu] * ym2);
        dout[orow + 256 + hu] = f2bf(x_l[b][256 + hu] * ym2);
      }
      if (t < 99) {
        p1_gemm(WihA, WhhA, x_l, h_l, scr, tid, hug);
        if (tid < 128) {
          int b = tid >> 4, dl = tid & 15;
          int bglob = bg * 8 + b;
          float g4[4];
#pragma unroll
          for (int gate = 0; gate < 4; ++gate) {
            int r2 = dl * 4 + gate;
            int wrow2 = gate * 256 + hug * 16 + dl;
            g4[gate] = scr[r2][b * 4] + scr[r2][b * 4 + 1] + scr[r2][b * 4 + 2] +
                       scr[r2][b * 4 + 3] + bf2f(bihA[wrow2]) + bf2f(bhhA[wrow2]);
          }
          float* gp = g_att + (size_t)(bglob * 256 + hug * 16 + dl) * 4;
          gstore(gp + 0, g4[0]);
          gstore(gp + 1, g4[1]);
          gstore(gp + 2, g4[2]);
          gstore(gp + 3, g4[3]);
        }
      }
    } else {
      if (t >= 1) {
        int s = t - 1;
        for (int i = tid; i < 2048; i += 256) {
          int b = i >> 8, d = i & 255;
          int bglob = bg * 8 + b;
          float ym = bf2f(y_mask[bglob * 100 + s + 1]);
          const float* cp = ctx_part + (size_t)bglob * 4 * 257;
          float s0 = gload(cp + d) + gload(cp + 257 + d) +
                     gload(cp + 2 * 257 + d) + gload(cp + 3 * 257 + d);
          float es = gload(cp + 256) + gload(cp + 257 + 256) +
                     gload(cp + 2 * 257 + 256) + gload(cp + 3 * 257 + 256);
          float cx = s0 / fmaxf(es, 1e-30f);
          x_l[b][d] = gload(h_att_g + bglob * 256 + d) * ym;
          x_l[b][256 + d] = cx * ym;
          h_l[b][d] = gload(h_dec + (s & 1) * 16384 + bglob * 256 + d);
        }
        __syncthreads();
        p1_gemm(WihD, WhhD, x_l, h_l, scr, tid, hug);
        if (tid < 128) {
          int b = tid >> 4, dl = tid & 15;
          int bglob = bg * 8 + b;
          float g4[4];
#pragma unroll
          for (int gate = 0; gate < 4; ++gate) {
            int r2 = dl * 4 + gate;
            int wrow2 = gate * 256 + hug * 16 + dl;
            g4[gate] = scr[r2][b * 4] + scr[r2][b * 4 + 1] + scr[r2][b * 4 + 2] +
                       scr[r2][b * 4 + 3] + bf2f(bihD[wrow2]) + bf2f(bhhD[wrow2]);
          }
          float ii = sigm(g4[0]), ff = sigm(g4[1]), gg = tanh_(g4[2]), oo = sigm(g4[3]);
          float cn = ff * c_dec_reg + ii * gg;
          c_dec_reg = cn;
          float hn = oo * tanh_(cn);
          int hu_g = hug * 16 + dl;
          gstore(h_dec + ((s + 1) & 1) * 16384 + bglob * 256 + hu_g, hn);
          float ym = bf2f(y_mask[bglob * 100 + s + 1]);
          dout[((size_t)bglob * 99 + s) * 768 + 512 + hu_g] = f2bf(hn * ym);
        }
      }
    }
    if (t == 99) break;
    gbar2(slots, (u32)(2 * t + 1));

    {
      int b = b2;
      const float* gp = g_att + (size_t)(b * 256 + tid) * 4;
      float g0 = gload(gp + 0), g1 = gload(gp + 1);
      float g2 = gload(gp + 2), g3 = gload(gp + 3);
      float ii = sigm(g0), ff = sigm(g1), gg = tanh_(g2), oo = sigm(g3);
      float cn = ff * c_att_reg + ii * gg;
      c_att_reg = cn;
      float hn = oo * tanh_(cn);
      if (tc == 0) gstore(h_att_g + b * 256 + tid, hn);
      hs_l[tid] = hn;
      __syncthreads();
      float st = bf2f(v_b[tid]);
#pragma unroll 16
      for (int k = 0; k < 256; ++k)
        st += hs_l[k] * bf2f(vwT[(size_t)k * 256 + tid]);
      ts_l[tid] = tanh_(st);
      __syncthreads();
      int tg = tc * 256 + tid;
      const u16* ar = Ta + ((size_t)(b * 1024 + tg)) * 256;
      float s = 0.f;
#pragma unroll 8
      for (int d8 = 0; d8 < 256; d8 += 8) {
        float af[8];
        bf8_to_f32(*(const uint4*)(ar + d8), af);
#pragma unroll
        for (int j = 0; j < 8; ++j) {
          float ts = ts_l[d8 + j], ta = af[j];
          float u = ts + ta;
          float v = fmaf(ts, ta, 1.f);
          s = fmaf(wv_l[d8 + j] * u, __builtin_amdgcn_rcpf(fmaxf(v, 1e-6f)), s);
        }
      }
      s += (bf2f(x_mask[b * 1024 + tg]) - 1.f) * 1e30f;
      s = fminf(s, 80.f);
      float p = __builtin_amdgcn_exp2f(s * LOG2E);
      p_l[tid] = p;
      float wsum = p;
#pragma unroll
      for (int off = 32; off; off >>= 1) wsum += __shfl_down(wsum, off);
      if ((tid & 63) == 0) red_l[tid >> 6] = wsum;
      __syncthreads();
      const u16* er = eout + ((size_t)(b * 1024 + tc * 256)) * 256;
      float a0 = 0.f;
#pragma unroll 16
      for (int tt = 0; tt < 256; ++tt)
        a0 += p_l[tt] * bf2f(er[(size_t)tt * 256 + tid]);
      float* cslot = ctx_part + (size_t)(b * 4 + tc) * 257;
      gstore(cslot + tid, a0);
      if (tid == 0)
        gstore(cslot + 256, red_l[0] + red_l[1] + red_l[2] + red_l[3]);
    }
    gbar2(slots, (u32)(2 * t + 2));
  }
}

extern "C" void kernel_launch(void* const* d_in, const int* in_sizes, int n_in,
                              void* d_out, int out_size, void* d_ws, size_t ws_size,
                              hipStream_t stream) {
  (void)in_sizes; (void)n_in; (void)out_size; (void)ws_size;
  const void* eout    = d_in[0];
  const void* x_mask  = d_in[1];
  const int*  y       = (const int*)d_in[2];
  const void* y_mask  = d_in[3];
  const void* emb     = d_in[4];
  const void* w_w     = d_in[5];
  const void* w_b     = d_in[6];
  const void* v_w     = d_in[7];
  const void* v_b     = d_in[8];
  const void* w_att_v = d_in[9];
  const void* Wih_att = d_in[10];
  const void* Whh_att = d_in[11];
  const void* bih_att = d_in[12];
  const void* bhh_att = d_in[13];
  const void* Wih_dec = d_in[14];
  const void* Whh_dec = d_in[15];
  const void* bih_dec = d_in[16];
  const void* bhh_dec = d_in[17];
  const void* cls_w   = d_in[18];
  const void* cls_b   = d_in[19];
  const u32* probe = (const u32*)x_mask;

  // d_out scratch: Ta then eoutB (fp32 mode only). Dead before k_logit.
  u16* TaB   = (u16*)d_out;
  u16* eoutB = TaB + 16777216;

  // ws layout (bytes), total ~22.7 MB
  char* w = (char*)d_ws;
  u32*   slots    = (u32*)(w + 0);           // 32768, zeroed
  float* h_dec    = (float*)(w + 32768);     // 131072, zeroed
  float* h_att_g  = (float*)(w + 163840);    // 65536, zeroed
  const size_t ZB = 229376;
  float* g_att    = (float*)(w + 229376);    // 262144
  float* ctx_part = (float*)(w + 491520);    // 263168
  u16*   vwT      = (u16*)(w + 754688);      // 131072
  u16*   dout     = (u16*)(w + 885760);      // 9732096 -> 10617856
  u16*   embB     = (u16*)(w + 10617856);
  u16*   WihAB    = (u16*)(w + 12785152);
  u16*   WhhAB    = (u16*)(w + 13833728);
  u16*   WihDB    = (u16*)(w + 14358016);
  u16*   WhhDB    = (u16*)(w + 15406592);
  u16*   bihAB    = (u16*)(w + 15930880);
  u16*   bhhAB    = (u16*)(w + 15932928);
  u16*   bihDB    = (u16*)(w + 15934976);
  u16*   bhhDB    = (u16*)(w + 15937024);
  u16*   v_bB     = (u16*)(w + 15939072);
  u16*   wavB     = (u16*)(w + 15939584);
  u16*   w_wB     = (u16*)(w + 15940096);
  u16*   w_bB     = (u16*)(w + 16071168);
  u16*   x_maskB  = (u16*)(w + 16071680);
  u16*   y_maskB  = (u16*)(w + 16202752);
  u16*   cls_wB   = (u16*)(w + 16215552);
  u16*   cls_bB   = (u16*)(w + 22717440);

  Segs S;
  const void* srcs[NSEG] = {eout, emb, Wih_att, Whh_att, Wih_dec, Whh_dec,
                            bih_att, bhh_att, bih_dec, bhh_dec, v_b, w_att_v,
                            w_w, w_b, x_mask, y_mask, cls_w, cls_b};
  u16* dsts[NSEG] = {eoutB, embB, WihAB, WhhAB, WihDB, WhhDB,
                     bihAB, bhhAB, bihDB, bhhDB, v_bB, wavB,
                     w_wB, w_bB, x_maskB, y_maskB, cls_wB, cls_bB};
  int ns[NSEG] = {16777216, 1083648, 524288, 262144, 524288, 262144,
                  1024, 1024, 1024, 1024, 256, 256,
                  65536, 256, 65536, 6400, 3250944, 4233};
  for (int i = 0; i < NSEG; ++i) { S.src[i] = srcs[i]; S.dst[i] = dsts[i]; S.n[i] = ns[i]; }

  hipMemsetAsync(d_ws, 0, ZB, stream);
  hipLaunchKernelGGL(k_convert, dim3(4096, NSEG), dim3(256), 0, stream, S, probe);
  hipLaunchKernelGGL(k_vwt, dim3(256), dim3(256), 0, stream, v_w, vwT, probe);
  hipLaunchKernelGGL(k_atth, dim3(1024, 4), dim3(256), 0, stream,
                     eout, eoutB, w_w, w_wB, w_b, w_bB, TaB, probe);
  hipLaunchKernelGGL(k_scan, dim3(NBLK), dim3(256), 0, stream,
                     eout, eoutB, x_mask, x_maskB, y, y_mask, y_maskB,
                     emb, embB, v_b, v_bB, w_att_v, wavB,
                     Wih_att, WihAB, Whh_att, WhhAB, bih_att, bihAB, bhh_att, bhhAB,
                     Wih_dec, WihDB, Whh_dec, WhhDB, bih_dec, bihDB, bhh_dec, bhhDB,
                     slots, h_dec, h_att_g, g_att, ctx_part, vwT, TaB, dout);
  hipLaunchKernelGGL(k_logit, dim3(99, 67), dim3(256), 0, stream,
                     dout, cls_w, cls_wB, cls_b, cls_bB, d_out, probe);
}